// Round 6
// baseline (12407.206 us; speedup 1.0000x reference)
//
#include <hip/hip_runtime.h>
#include <hip/hip_bf16.h>

#define Sv 256
#define Hv 16
#define LR 0.1f
#define SCALE (2.0f / 8192.0f)   // dLoss/dpred: 2/(B*H*D)

using bf16x8 = __attribute__((ext_vector_type(8))) short;
using bf16x4 = __attribute__((ext_vector_type(4))) short;
using f32x4  = __attribute__((ext_vector_type(4))) float;
using u32x4  = __attribute__((ext_vector_type(4))) unsigned;
#define MFMA16(A, B, C) __builtin_amdgcn_mfma_f32_16x16x32_bf16(A, B, C, 0, 0, 0)

// ---------------------------------------------------------------------------
// Dynamic LDS layout (byte offsets). One head per block, ONE WAVE per block.
// Weight planes: ushort rows pitch 136 (hi[64]|lo[64]|pad). W2R hi-only pitch 72.
// Activation planes: u32[16][68], element = hi | lo<<16; rows 8..15 zeroed pad.
// KT: u32[64][8] column-major k for dW1 A-operand.
// ---------------------------------------------------------------------------
constexpr int O_W1T = 0;         // [f][d]
constexpr int O_W2T = 17408;     // [d][f]
constexpr int O_LwT = 34816;     // [e][d]
constexpr int O_LwR = 52224;     // [d][e]
constexpr int O_W2R = 69632;     // [f][d] hi-only, 64x72
constexpr int O_Kp  = 78848;
constexpr int O_Hp  = 83200;
constexpr int O_Zp  = 87552;
constexpr int O_DPp = 91904;
constexpr int O_DOp = 96256;
constexpr int O_KT  = 100608;
constexpr int LDS_SCAN = 102656;

// ---------------------------------------------------------------------------
// Helpers
// ---------------------------------------------------------------------------
__device__ __forceinline__ short bf_rn(float v) {
    unsigned u = __float_as_uint(v);
    unsigned r = u + 0x7fffu + ((u >> 16) & 1u);
    return (short)(r >> 16);
}
__device__ __forceinline__ void cvt1(float v, short &hi, short &lo) {
    hi = bf_rn(v);
    float hf = __uint_as_float(((unsigned)(unsigned short)hi) << 16);
    lo = bf_rn(v - hf);
}
__device__ __forceinline__ float bf2f(short u) {
    return __uint_as_float(((unsigned)(unsigned short)u) << 16);
}
__device__ __forceinline__ unsigned pkbf(float a, float b) {
    __hip_bfloat162 r = __float22bfloat162_rn(make_float2(a, b));
    unsigned u;
    __builtin_memcpy(&u, &r, sizeof(u));
    return u;
}
__device__ __forceinline__ void cvt2pk(float a, float b, unsigned &hp, unsigned &lp) {
    hp = pkbf(a, b);
    float ha = __uint_as_float(hp << 16);
    float hb = __uint_as_float(hp & 0xffff0000u);
    lp = pkbf(a - ha, b - hb);
}
__device__ __forceinline__ bf16x8 mk8(unsigned a, unsigned b, unsigned c, unsigned d) {
    union { unsigned u[4]; bf16x8 v; } x;
    x.u[0] = a; x.u[1] = b; x.u[2] = c; x.u[3] = d;
    return x.v;
}
// v0..v3 = rows 4q+0..3 at one column. u0..u3 = interleaved hi|lo<<16 per row.
// hA/lA = packed (hi0|hi1<<16)/(lo0|lo1<<16); hB/lB same for rows 2,3.
__device__ __forceinline__ void pack4(float v0, float v1, float v2, float v3,
                                      unsigned &u0, unsigned &u1, unsigned &u2,
                                      unsigned &u3, unsigned &hA, unsigned &lA,
                                      unsigned &hB, unsigned &lB) {
    cvt2pk(v0, v1, hA, lA);
    cvt2pk(v2, v3, hB, lB);
    u0 = (hA & 0xffffu) | (lA << 16);
    u1 = (hA >> 16) | (lA & 0xffff0000u);
    u2 = (hB & 0xffffu) | (lB << 16);
    u3 = (hB >> 16) | (lB & 0xffff0000u);
}
__device__ __forceinline__ void unp8(u32x4 a, u32x4 b, bf16x8 &hi, bf16x8 &lo) {
    union { unsigned u[4]; bf16x8 v; } H, L;
    H.u[0] = (a[0] & 0xffffu) | (a[1] << 16);
    H.u[1] = (a[2] & 0xffffu) | (a[3] << 16);
    H.u[2] = (b[0] & 0xffffu) | (b[1] << 16);
    H.u[3] = (b[2] & 0xffffu) | (b[3] << 16);
    L.u[0] = (a[0] >> 16) | (a[1] & 0xffff0000u);
    L.u[1] = (a[2] >> 16) | (a[3] & 0xffff0000u);
    L.u[2] = (b[0] >> 16) | (b[1] & 0xffff0000u);
    L.u[3] = (b[2] >> 16) | (b[3] & 0xffff0000u);
    hi = H.v; lo = L.v;
}
// A-frags {hi0,lo0,hi1,lo1} of activation plane P (rows c, k-cols 8q+j / +32)
__device__ __forceinline__ void loadA4(const unsigned *P, int c, int q, bf16x8 f[4]) {
    const unsigned *p = P + c * 68 + 8 * q;
    unp8(*(const u32x4 *)p, *(const u32x4 *)(p + 4), f[0], f[1]);
    unp8(*(const u32x4 *)(p + 32), *(const u32x4 *)(p + 36), f[2], f[3]);
}
// B-frags {bh0,bl0,bh1,bl1} of weight plane W, output tile nt
__device__ __forceinline__ void loadB4(const unsigned short *W, int nt, int c,
                                       int q, bf16x8 g[4]) {
    const unsigned short *br = W + (16 * nt + c) * 136 + 8 * q;
    g[0] = *(const bf16x8 *)br;
    g[1] = *(const bf16x8 *)(br + 64);
    g[2] = *(const bf16x8 *)(br + 32);
    g[3] = *(const bf16x8 *)(br + 96);
}
__device__ __forceinline__ f32x4 mm4(const bf16x8 *A, const bf16x8 *B) {
    f32x4 x0 = {0.f, 0.f, 0.f, 0.f}, x1 = {0.f, 0.f, 0.f, 0.f};
    x0 = MFMA16(A[0], B[0], x0); x1 = MFMA16(A[2], B[2], x1);
    x0 = MFMA16(A[1], B[0], x0); x1 = MFMA16(A[3], B[2], x1);
    x0 = MFMA16(A[0], B[1], x0); x1 = MFMA16(A[2], B[3], x1);
    x0 = MFMA16(A[1], B[1], x0); x1 = MFMA16(A[3], B[3], x1);
    return x0 + x1;
}
__device__ __forceinline__ float red16(float v) {
    v += __shfl_xor(v, 1);
    v += __shfl_xor(v, 2);
    v += __shfl_xor(v, 4);
    v += __shfl_xor(v, 8);
    return v;
}
__device__ __forceinline__ float fast_tanh(float u) {
    u = fminf(fmaxf(u, -10.f), 10.f);
    float e = __expf(2.0f * u);
    return (e - 1.0f) / (e + 1.0f);
}
__device__ __forceinline__ void gelu_both(float x, float &g, float &dg) {
    const float C0 = 0.7978845608028654f, A0 = 0.044715f;
    float x2 = x * x;
    float u = C0 * x * (1.0f + A0 * x2);
    float t = fast_tanh(u);
    g = 0.5f * x * (1.0f + t);
    float du = C0 * (1.0f + 3.0f * A0 * x2);
    dg = 0.5f * (1.0f + t) + 0.5f * x * (1.0f - t * t) * du;
}
__device__ __forceinline__ float gelu_f(float x) {
    const float C0 = 0.7978845608028654f, A0 = 0.044715f;
    float u = C0 * x * (1.0f + A0 * x * x);
    return 0.5f * x * (1.0f + fast_tanh(u));
}
// W[row][colbase..+3] (hi/lo planes, pitch 136) -= LR*g
__device__ __forceinline__ void rmw1(unsigned short *WT, int row, int colbase,
                                     f32x4 g) {
    unsigned short *ph = WT + row * 136 + colbase;
    bf16x4 oh = *(bf16x4 *)ph, ol = *(bf16x4 *)(ph + 64), nh, nl;
#pragma unroll
    for (int r = 0; r < 4; ++r) {
        float wv = bf2f(oh[r]) + bf2f(ol[r]) - LR * g[r];
        short hh, ll;
        cvt1(wv, hh, ll);
        nh[r] = hh; nl[r] = ll;
    }
    *(bf16x4 *)ph = nh;
    *(bf16x4 *)(ph + 64) = nl;
}
// same + mirror new hi into W2R[f][d] (f = wrRow+r, d = wrCol)
__device__ __forceinline__ void rmw2(unsigned short *WT, unsigned short *WR,
                                     int row, int colbase, int wrRow, int wrCol,
                                     f32x4 g) {
    unsigned short *ph = WT + row * 136 + colbase;
    bf16x4 oh = *(bf16x4 *)ph, ol = *(bf16x4 *)(ph + 64), nh, nl;
#pragma unroll
    for (int r = 0; r < 4; ++r) {
        float wv = bf2f(oh[r]) + bf2f(ol[r]) - LR * g[r];
        short hh, ll;
        cvt1(wv, hh, ll);
        nh[r] = hh; nl[r] = ll;
        WR[(wrRow + r) * 72 + wrCol] = (unsigned short)hh;
    }
    *(bf16x4 *)ph = nh;
    *(bf16x4 *)(ph + 64) = nl;
}

// ---------------------------------------------------------------------------
// TTT scan: 16 blocks x 64 threads (ONE WAVE per head) — zero barriers.
// ---------------------------------------------------------------------------
__global__ __launch_bounds__(64, 1) void ttt_scan(
    const float *__restrict__ q_g, const float *__restrict__ k_g,
    const float *__restrict__ v_g, float *__restrict__ out_g,
    const float *__restrict__ fw_w1, const float *__restrict__ fw_b1,
    const float *__restrict__ fw_w2, const float *__restrict__ fw_b2,
    const float *__restrict__ fw_lng, const float *__restrict__ fw_lnb,
    const float *__restrict__ loss_w, const float *__restrict__ loss_bv,
    const float *__restrict__ ttt_gv, const float *__restrict__ ttt_bv) {
    extern __shared__ char smem[];
    unsigned short *W1T = (unsigned short *)(smem + O_W1T);
    unsigned short *W2T = (unsigned short *)(smem + O_W2T);
    unsigned short *LwT = (unsigned short *)(smem + O_LwT);
    unsigned short *LwR = (unsigned short *)(smem + O_LwR);
    unsigned short *W2R = (unsigned short *)(smem + O_W2R);
    unsigned *Kp = (unsigned *)(smem + O_Kp);
    unsigned *Hp = (unsigned *)(smem + O_Hp);
    unsigned *Zp = (unsigned *)(smem + O_Zp);
    unsigned *DPp = (unsigned *)(smem + O_DPp);
    unsigned *DOp = (unsigned *)(smem + O_DOp);
    unsigned *KT = (unsigned *)(smem + O_KT);

    const int lane = threadIdx.x;
    const int c = lane & 15, q = lane >> 4;
    const int h = blockIdx.x;

    // ---- init weights into planes (single wave: in-order LDS, no barriers)
    for (int i = lane; i < 4096; i += 64) {
        int r = i >> 6, cc = i & 63;
        short hi, lo;
        cvt1(fw_w1[h * 4096 + i], hi, lo);   // W1[d=r][f=cc]
        W1T[cc * 136 + r] = (unsigned short)hi;
        W1T[cc * 136 + 64 + r] = (unsigned short)lo;
        cvt1(fw_w2[h * 4096 + i], hi, lo);   // W2[f=r][d=cc]
        W2T[cc * 136 + r] = (unsigned short)hi;
        W2T[cc * 136 + 64 + r] = (unsigned short)lo;
        W2R[r * 72 + cc] = (unsigned short)hi;
        cvt1(loss_w[i], hi, lo);             // Lw[d=r][e=cc]
        LwT[cc * 136 + r] = (unsigned short)hi;
        LwT[cc * 136 + 64 + r] = (unsigned short)lo;
        LwR[r * 136 + cc] = (unsigned short)hi;
        LwR[r * 136 + 64 + cc] = (unsigned short)lo;
    }
    for (int i = lane; i < 5 * 8 * 68; i += 64) {
        int a = i / (8 * 68), rem = i % (8 * 68);
        unsigned *P = (a == 0) ? Kp : (a == 1) ? Hp : (a == 2) ? Zp
                      : (a == 3) ? DPp : DOp;
        P[(8 + rem / 68) * 68 + rem % 68] = 0u;
    }
    // ---- vector params in registers (col = 16nt+c), updated in-register
    float b1v[4], b2v[4], lgv[4], lbv[4], Lbv[4], tGv[4], tBv[4];
#pragma unroll
    for (int nt = 0; nt < 4; ++nt) {
        int col = 16 * nt + c;
        b1v[nt] = fw_b1[h * 64 + col];
        b2v[nt] = fw_b2[h * 64 + col];
        lgv[nt] = fw_lng[h * 64 + col];
        lbv[nt] = fw_lnb[h * 64 + col];
        Lbv[nt] = loss_bv[col];
        tGv[nt] = ttt_gv[h * 64 + col];
        tBv[nt] = ttt_bv[h * 64 + col];
    }

    // prefetch token 0 in C-layout: element [nt*4+r] = row 4q+r, col 16nt+c
    float pkr[16], pvr[16], pqr[16];
#pragma unroll
    for (int j = 0; j < 16; ++j) { pkr[j] = 0.f; pvr[j] = 0.f; pqr[j] = 0.f; }
    if (q < 2) {
#pragma unroll
        for (int nt = 0; nt < 4; ++nt)
#pragma unroll
            for (int r = 0; r < 4; ++r) {
                long idx = (((long)(4 * q + r) * Sv + 0) * Hv + h) * 64 + 16 * nt + c;
                pkr[nt * 4 + r] = k_g[idx];
                pvr[nt * 4 + r] = v_g[idx];
                pqr[nt * 4 + r] = q_g[idx];
            }
    }

#pragma unroll 1
    for (int t = 0; t < Sv; ++t) {
        // ---- stage k into Kp (plane) + KT (column-major); tg in regs
        float tgr[16];
#pragma unroll
        for (int nt = 0; nt < 4; ++nt) {
#pragma unroll
            for (int r = 0; r < 4; ++r)
                tgr[nt * 4 + r] = pvr[nt * 4 + r] - pkr[nt * 4 + r];
            unsigned u0, u1, u2, u3, hA, lA, hB, lB;
            pack4(pkr[nt * 4 + 0], pkr[nt * 4 + 1], pkr[nt * 4 + 2],
                  pkr[nt * 4 + 3], u0, u1, u2, u3, hA, lA, hB, lB);
            if (q < 2) {
                int col = 16 * nt + c;
                Kp[(4 * q + 0) * 68 + col] = u0;
                Kp[(4 * q + 1) * 68 + col] = u1;
                Kp[(4 * q + 2) * 68 + col] = u2;
                Kp[(4 * q + 3) * 68 + col] = u3;
                KT[col * 8 + 4 * q + 0] = u0;
                KT[col * 8 + 4 * q + 1] = u1;
                KT[col * 8 + 4 * q + 2] = u2;
                KT[col * 8 + 4 * q + 3] = u3;
            }
        }
        // ---- prefetch t+1 (latency hidden under the whole token)
        float pkn[16], pvn[16], pqn[16];
#pragma unroll
        for (int j = 0; j < 16; ++j) { pkn[j] = 0.f; pvn[j] = 0.f; pqn[j] = 0.f; }
        if (q < 2 && t + 1 < Sv) {
#pragma unroll
            for (int nt = 0; nt < 4; ++nt)
#pragma unroll
                for (int r = 0; r < 4; ++r) {
                    long idx = (((long)(4 * q + r) * Sv + (t + 1)) * Hv + h) * 64 + 16 * nt + c;
                    pkn[nt * 4 + r] = k_g[idx];
                    pvn[nt * 4 + r] = v_g[idx];
                    pqn[nt * 4 + r] = q_g[idx];
                }
        }
        // ---- k A-frags (rows c) and k column frags for dW1 (q==0 only)
        bf16x8 kaf[4];
        loadA4(Kp, c, q, kaf);
        bf16x8 k0h[4], k0l[4];
        const bf16x8 z8 = {0, 0, 0, 0, 0, 0, 0, 0};
#pragma unroll
        for (int mt = 0; mt < 4; ++mt) {
            u32x4 a = *(const u32x4 *)&KT[(16 * mt + c) * 8];
            u32x4 b = *(const u32x4 *)&KT[(16 * mt + c) * 8 + 4];
            bf16x8 hh, ll;
            unp8(a, b, hh, ll);
            k0h[mt] = (q == 0) ? hh : z8;
            k0l[mt] = (q == 0) ? ll : z8;
        }

        bf16x8 Bf[4];
        f32x4 acc[4];
        float xh[16], rs[4];

#pragma unroll 1
        for (int step = 0; step < 4; ++step) {
            // ---- F1: h = gelu(k@W1 + b1)
#pragma unroll
            for (int nt = 0; nt < 4; ++nt) {
                loadB4(W1T, nt, c, q, Bf);
                acc[nt] = mm4(kaf, Bf);
            }
            float gd[16];
            unsigned hp01[4], hp23[4], lp01[4], lp23[4];
#pragma unroll
            for (int nt = 0; nt < 4; ++nt) {
                float g0, g1, g2, g3;
                gelu_both(acc[nt][0] + b1v[nt], g0, gd[nt * 4 + 0]);
                gelu_both(acc[nt][1] + b1v[nt], g1, gd[nt * 4 + 1]);
                gelu_both(acc[nt][2] + b1v[nt], g2, gd[nt * 4 + 2]);
                gelu_both(acc[nt][3] + b1v[nt], g3, gd[nt * 4 + 3]);
                unsigned u0, u1, u2, u3;
                pack4(g0, g1, g2, g3, u0, u1, u2, u3,
                      hp01[nt], lp01[nt], hp23[nt], lp23[nt]);
                if (q < 2) {
                    int col = 16 * nt + c;
                    Hp[(4 * q + 0) * 68 + col] = u0;
                    Hp[(4 * q + 1) * 68 + col] = u1;
                    Hp[(4 * q + 2) * 68 + col] = u2;
                    Hp[(4 * q + 3) * 68 + col] = u3;
                }
            }
            // ---- F2: o = h@W2 + b2 ; in-wave LN
            bf16x8 haf[4];
            loadA4(Hp, c, q, haf);
#pragma unroll
            for (int nt = 0; nt < 4; ++nt) {
                loadB4(W2T, nt, c, q, Bf);
                acc[nt] = mm4(haf, Bf);
            }
            float o[16];
#pragma unroll
            for (int nt = 0; nt < 4; ++nt)
#pragma unroll
                for (int r = 0; r < 4; ++r) o[nt * 4 + r] = acc[nt][r] + b2v[nt];
#pragma unroll
            for (int r = 0; r < 4; ++r) {
                float s = o[r] + o[4 + r] + o[8 + r] + o[12 + r];
                float s2 = o[r] * o[r] + o[4 + r] * o[4 + r] +
                           o[8 + r] * o[8 + r] + o[12 + r] * o[12 + r];
                s = red16(s);
                s2 = red16(s2);
                float mu = s * (1.f / 64.f);
                float var = s2 * (1.f / 64.f) - mu * mu;
                float rr = rsqrtf(var + 1e-5f);
                rs[r] = rr;
#pragma unroll
                for (int nt = 0; nt < 4; ++nt)
                    xh[nt * 4 + r] = (o[nt * 4 + r] - mu) * rr;
            }
#pragma unroll
            for (int nt = 0; nt < 4; ++nt) {
                float z0 = xh[nt * 4 + 0] * lgv[nt] + lbv[nt];
                float z1 = xh[nt * 4 + 1] * lgv[nt] + lbv[nt];
                float z2 = xh[nt * 4 + 2] * lgv[nt] + lbv[nt];
                float z3 = xh[nt * 4 + 3] * lgv[nt] + lbv[nt];
                unsigned u0, u1, u2, u3, hA, lA, hB, lB;
                pack4(z0, z1, z2, z3, u0, u1, u2, u3, hA, lA, hB, lB);
                if (q < 2) {
                    int col = 16 * nt + c;
                    Zp[(4 * q + 0) * 68 + col] = u0;
                    Zp[(4 * q + 1) * 68 + col] = u1;
                    Zp[(4 * q + 2) * 68 + col] = u2;
                    Zp[(4 * q + 3) * 68 + col] = u3;
                }
            }
            // ---- F3: dp = (z@Lw + Lb - tg)*SCALE
            bf16x8 zaf[4];
            loadA4(Zp, c, q, zaf);
#pragma unroll
            for (int nt = 0; nt < 4; ++nt) {
                loadB4(LwT, nt, c, q, Bf);
                acc[nt] = mm4(zaf, Bf);
            }
#pragma unroll
            for (int nt = 0; nt < 4; ++nt) {
                float d0 = (acc[nt][0] + Lbv[nt] - tgr[nt * 4 + 0]) * SCALE;
                float d1 = (acc[nt][1] + Lbv[nt] - tgr[nt * 4 + 1]) * SCALE;
                float d2 = (acc[nt][2] + Lbv[nt] - tgr[nt * 4 + 2]) * SCALE;
                float d3 = (acc[nt][3] + Lbv[nt] - tgr[nt * 4 + 3]) * SCALE;
                unsigned u0, u1, u2, u3, hA, lA, hB, lB;
                pack4(d0, d1, d2, d3, u0, u1, u2, u3, hA, lA, hB, lB);
                if (q < 2) {
                    int col = 16 * nt + c;
                    DPp[(4 * q + 0) * 68 + col] = u0;
                    DPp[(4 * q + 1) * 68 + col] = u1;
                    DPp[(4 * q + 2) * 68 + col] = u2;
                    DPp[(4 * q + 3) * 68 + col] = u3;
                }
            }
            // ---- B1: dz = dp @ Lw^T ; in-wave LN-backward
            bf16x8 paf[4];
            loadA4(DPp, c, q, paf);
#pragma unroll
            for (int nt = 0; nt < 4; ++nt) {
                loadB4(LwR, nt, c, q, Bf);
                acc[nt] = mm4(paf, Bf);   // dz in C-layout
            }
            float dov[16];
#pragma unroll
            for (int r = 0; r < 4; ++r) {
                float a0 = acc[0][r] * lgv[0], a1 = acc[1][r] * lgv[1];
                float a2 = acc[2][r] * lgv[2], a3 = acc[3][r] * lgv[3];
                float s1 = a0 + a1 + a2 + a3;
                float s2 = a0 * xh[r] + a1 * xh[4 + r] + a2 * xh[8 + r] +
                           a3 * xh[12 + r];
                s1 = red16(s1) * (1.f / 64.f);
                s2 = red16(s2) * (1.f / 64.f);
                dov[0 * 4 + r] = rs[r] * (a0 - s1 - xh[r] * s2);
                dov[1 * 4 + r] = rs[r] * (a1 - s1 - xh[4 + r] * s2);
                dov[2 * 4 + r] = rs[r] * (a2 - s1 - xh[8 + r] * s2);
                dov[3 * 4 + r] = rs[r] * (a3 - s1 - xh[12 + r] * s2);
            }
            // lg/lb updates (after dov computed with old lgv)
#pragma unroll
            for (int nt = 0; nt < 4; ++nt) {
                float tl = acc[nt][0] * xh[nt * 4 + 0] + acc[nt][1] * xh[nt * 4 + 1] +
                           acc[nt][2] * xh[nt * 4 + 2] + acc[nt][3] * xh[nt * 4 + 3];
                float tb = acc[nt][0] + acc[nt][1] + acc[nt][2] + acc[nt][3];
                tl += __shfl_xor(tl, 16); tl += __shfl_xor(tl, 32);
                tb += __shfl_xor(tb, 16); tb += __shfl_xor(tb, 32);
                lgv[nt] -= LR * tl;
                lbv[nt] -= LR * tb;
            }
            unsigned doH01[4], doH23[4], doL01[4], doL23[4];
#pragma unroll
            for (int nt = 0; nt < 4; ++nt) {
                unsigned u0, u1, u2, u3;
                pack4(dov[nt * 4 + 0], dov[nt * 4 + 1], dov[nt * 4 + 2],
                      dov[nt * 4 + 3], u0, u1, u2, u3,
                      doH01[nt], doL01[nt], doH23[nt], doL23[nt]);
                if (q < 2) {
                    int col = 16 * nt + c;
                    DOp[(4 * q + 0) * 68 + col] = u0;
                    DOp[(4 * q + 1) * 68 + col] = u1;
                    DOp[(4 * q + 2) * 68 + col] = u2;
                    DOp[(4 * q + 3) * 68 + col] = u3;
                }
                float tb = dov[nt * 4 + 0] + dov[nt * 4 + 1] + dov[nt * 4 + 2] +
                           dov[nt * 4 + 3];
                tb += __shfl_xor(tb, 16); tb += __shfl_xor(tb, 32);
                b2v[nt] -= LR * tb;
            }
            // ---- B2: dh = do @ W2^T (hi-only) ; da = dh * gelu'
            bf16x8 oaf[4];
            loadA4(DOp, c, q, oaf);
#pragma unroll
            for (int nt = 0; nt < 4; ++nt) {
                const unsigned short *br = W2R + (16 * nt + c) * 72 + 8 * q;
                bf16x8 bh0 = *(const bf16x8 *)br;
                bf16x8 bh1 = *(const bf16x8 *)(br + 32);
                f32x4 x0 = {0.f, 0.f, 0.f, 0.f}, x1 = {0.f, 0.f, 0.f, 0.f};
                x0 = MFMA16(oaf[0], bh0, x0); x1 = MFMA16(oaf[2], bh1, x1);
                x0 = MFMA16(oaf[1], bh0, x0); x1 = MFMA16(oaf[3], bh1, x1);
                acc[nt] = x0 + x1;
            }
            unsigned daH01[4], daH23[4], daL01[4], daL23[4];
#pragma unroll
            for (int nt = 0; nt < 4; ++nt) {
                float d0 = acc[nt][0] * gd[nt * 4 + 0];
                float d1 = acc[nt][1] * gd[nt * 4 + 1];
                float d2 = acc[nt][2] * gd[nt * 4 + 2];
                float d3 = acc[nt][3] * gd[nt * 4 + 3];
                unsigned u0, u1, u2, u3;
                pack4(d0, d1, d2, d3, u0, u1, u2, u3,
                      daH01[nt], daL01[nt], daH23[nt], daL23[nt]);
                float tb = d0 + d1 + d2 + d3;
                tb += __shfl_xor(tb, 16); tb += __shfl_xor(tb, 32);
                b1v[nt] -= LR * tb;
            }
            // ---- updates: build B/A frags via shfl_xor(16), MFMA, RMW planes
            bf16x8 daBh[4], daBl[4], doBh[4], doBl[4], hAh[4], hAl[4];
#pragma unroll
            for (int nt = 0; nt < 4; ++nt) {
                unsigned a1s = __shfl_xor(daH01[nt], 16), a2s = __shfl_xor(daH23[nt], 16);
                unsigned a3s = __shfl_xor(daL01[nt], 16), a4s = __shfl_xor(daL23[nt], 16);
                daBh[nt] = mk8(daH01[nt], daH23[nt], a1s, a2s);
                daBl[nt] = mk8(daL01[nt], daL23[nt], a3s, a4s);
                unsigned o1s = __shfl_xor(doH01[nt], 16), o2s = __shfl_xor(doH23[nt], 16);
                unsigned o3s = __shfl_xor(doL01[nt], 16), o4s = __shfl_xor(doL23[nt], 16);
                doBh[nt] = mk8(doH01[nt], doH23[nt], o1s, o2s);
                doBl[nt] = mk8(doL01[nt], doL23[nt], o3s, o4s);
                unsigned h1s = __shfl_xor(hp01[nt], 16), h2s = __shfl_xor(hp23[nt], 16);
                unsigned h3s = __shfl_xor(lp01[nt], 16), h4s = __shfl_xor(lp23[nt], 16);
                hAh[nt] = (q == 0) ? mk8(hp01[nt], hp23[nt], h1s, h2s) : z8;
                hAl[nt] = (q == 0) ? mk8(lp01[nt], lp23[nt], h3s, h4s) : z8;
            }
#pragma unroll
            for (int mt = 0; mt < 4; ++mt)
#pragma unroll
                for (int nt = 0; nt < 4; ++nt) {
                    f32x4 g = {0.f, 0.f, 0.f, 0.f};
                    g = MFMA16(k0h[mt], daBh[nt], g);
                    g = MFMA16(k0l[mt], daBh[nt], g);
                    g = MFMA16(k0h[mt], daBl[nt], g);
                    rmw1(W1T, 16 * nt + c, 16 * mt + 4 * q, g);
                }
#pragma unroll
            for (int mt = 0; mt < 4; ++mt)
#pragma unroll
                for (int nt = 0; nt < 4; ++nt) {
                    f32x4 g = {0.f, 0.f, 0.f, 0.f};
                    g = MFMA16(hAh[mt], doBh[nt], g);
                    g = MFMA16(hAl[mt], doBh[nt], g);
                    g = MFMA16(hAh[mt], doBl[nt], g);
                    rmw2(W2T, W2R, 16 * nt + c, 16 * mt + 4 * q,
                         16 * mt + 4 * q, 16 * nt + c, g);
                }
        }

        // ---- final forward with updated params
#pragma unroll
        for (int nt = 0; nt < 4; ++nt) {
            loadB4(W1T, nt, c, q, Bf);
            acc[nt] = mm4(kaf, Bf);
        }
#pragma unroll
        for (int nt = 0; nt < 4; ++nt) {
            float g0 = gelu_f(acc[nt][0] + b1v[nt]);
            float g1 = gelu_f(acc[nt][1] + b1v[nt]);
            float g2 = gelu_f(acc[nt][2] + b1v[nt]);
            float g3 = gelu_f(acc[nt][3] + b1v[nt]);
            unsigned u0, u1, u2, u3, hA, lA, hB, lB;
            pack4(g0, g1, g2, g3, u0, u1, u2, u3, hA, lA, hB, lB);
            if (q < 2) {
                int col = 16 * nt + c;
                Hp[(4 * q + 0) * 68 + col] = u0;
                Hp[(4 * q + 1) * 68 + col] = u1;
                Hp[(4 * q + 2) * 68 + col] = u2;
                Hp[(4 * q + 3) * 68 + col] = u3;
            }
        }
        bf16x8 haf[4];
        loadA4(Hp, c, q, haf);
#pragma unroll
        for (int nt = 0; nt < 4; ++nt) {
            loadB4(W2T, nt, c, q, Bf);
            acc[nt] = mm4(haf, Bf);
        }
        float o[16], z[16];
#pragma unroll
        for (int nt = 0; nt < 4; ++nt)
#pragma unroll
            for (int r = 0; r < 4; ++r) o[nt * 4 + r] = acc[nt][r] + b2v[nt];
#pragma unroll
        for (int r = 0; r < 4; ++r) {
            float s = o[r] + o[4 + r] + o[8 + r] + o[12 + r];
            float s2 = o[r] * o[r] + o[4 + r] * o[4 + r] + o[8 + r] * o[8 + r] +
                       o[12 + r] * o[12 + r];
            s = red16(s);
            s2 = red16(s2);
            float mu = s * (1.f / 64.f);
            float var = s2 * (1.f / 64.f) - mu * mu;
            float rr = rsqrtf(var + 1e-5f);
#pragma unroll
            for (int nt = 0; nt < 4; ++nt)
                z[nt * 4 + r] = (o[nt * 4 + r] - mu) * rr * lgv[nt] + lbv[nt];
        }
#pragma unroll
        for (int r = 0; r < 4; ++r) {
            float s = z[r] + z[4 + r] + z[8 + r] + z[12 + r];
            float s2 = z[r] * z[r] + z[4 + r] * z[4 + r] + z[8 + r] * z[8 + r] +
                       z[12 + r] * z[12 + r];
            s = red16(s);
            s2 = red16(s2);
            float mu2 = s * (1.f / 64.f);
            float var2 = s2 * (1.f / 64.f) - mu2 * mu2;
            float rr2 = rsqrtf(var2 + 1e-5f);
            if (q < 2) {
#pragma unroll
                for (int nt = 0; nt < 4; ++nt) {
                    float z2 = (z[nt * 4 + r] - mu2) * rr2 * tGv[nt] + tBv[nt];
                    long idx = (((long)(4 * q + r) * Sv + t) * Hv + h) * 64 + 16 * nt + c;
                    out_g[idx] = pqr[nt * 4 + r] + z2;
                }
            }
        }
        // rotate prefetch
#pragma unroll
        for (int j = 0; j < 16; ++j) {
            pkr[j] = pkn[j];
            pvr[j] = pvn[j];
            pqr[j] = pqn[j];
        }
    }
}

// ---------------------------------------------------------------------------
// fp32 GEMM: C[M,N] = A[M,K] @ B[K,N]; mode 1: C = gelu(acc) * gate_ln
// ---------------------------------------------------------------------------
__global__ __launch_bounds__(256) void gemm_f32(
    const float *__restrict__ A, const float *__restrict__ B,
    float *__restrict__ C, const float *__restrict__ gate_ln,
    int M, int N, int K, int mode) {
    __shared__ float As[16][68];
    __shared__ float Bs[16][64];
    const int tid = threadIdx.x;
    const int tx = tid & 15, ty = tid >> 4;
    const int bm = blockIdx.y * 64, bn = blockIdx.x * 64;

    float acc[4][4] = {};
    for (int k0 = 0; k0 < K; k0 += 16) {
        {
            int r = tid >> 2, kk = (tid & 3) * 4;
            float4 av = *(const float4 *)(A + (long)(bm + r) * K + k0 + kk);
            As[kk + 0][r] = av.x;
            As[kk + 1][r] = av.y;
            As[kk + 2][r] = av.z;
            As[kk + 3][r] = av.w;
            int rr = tid >> 4, cc = (tid & 15) * 4;
            float4 bv = *(const float4 *)(B + (long)(k0 + rr) * N + bn + cc);
            *(float4 *)&Bs[rr][cc] = bv;
        }
        __syncthreads();
#pragma unroll
        for (int kk = 0; kk < 16; ++kk) {
            float4 a4 = *(float4 *)&As[kk][ty * 4];
            float4 b4 = *(float4 *)&Bs[kk][tx * 4];
            float a[4] = {a4.x, a4.y, a4.z, a4.w};
            float b[4] = {b4.x, b4.y, b4.z, b4.w};
#pragma unroll
            for (int i = 0; i < 4; ++i)
#pragma unroll
                for (int j = 0; j < 4; ++j) acc[i][j] += a[i] * b[j];
        }
        __syncthreads();
    }
#pragma unroll
    for (int i = 0; i < 4; ++i) {
        int row = bm + ty * 4 + i;
        float4 out;
        float v[4];
#pragma unroll
        for (int j = 0; j < 4; ++j) {
            float val = acc[i][j];
            if (mode == 1) {
                int col = bn + tx * 4 + j;
                val = gelu_f(val) * gate_ln[(long)row * N + col];
            }
            v[j] = val;
        }
        out.x = v[0]; out.y = v[1]; out.z = v[2]; out.w = v[3];
        *(float4 *)(C + (long)row * N + bn + tx * 4) = out;
    }
}

// ---------------------------------------------------------------------------
// Row LayerNorm over 1024
// ---------------------------------------------------------------------------
__global__ __launch_bounds__(256) void row_ln(const float *__restrict__ in,
                                              float *__restrict__ out,
                                              const float *__restrict__ g,
                                              const float *__restrict__ b) {
    __shared__ float sred[4], s2red[4];
    const int row = blockIdx.x;
    const int tid = threadIdx.x;
    const float *x = in + (long)row * 1024;
    float4 v = *(const float4 *)(x + tid * 4);
    float s = v.x + v.y + v.z + v.w;
    float s2 = v.x * v.x + v.y * v.y + v.z * v.z + v.w * v.w;
#pragma unroll
    for (int m = 1; m <= 32; m <<= 1) {
        s += __shfl_xor(s, m);
        s2 += __shfl_xor(s2, m);
    }
    if ((tid & 63) == 0) {
        sred[tid >> 6] = s;
        s2red[tid >> 6] = s2;
    }
    __syncthreads();
    float S = sred[0] + sred[1] + sred[2] + sred[3];
    float S2 = s2red[0] + s2red[1] + s2red[2] + s2red[3];
    float mu = S * (1.f / 1024.f);
    float var = S2 * (1.f / 1024.f) - mu * mu;
    float rs = rsqrtf(var + 1e-5f);
    float o[4] = {v.x, v.y, v.z, v.w};
    float4 ov;
    float r[4];
#pragma unroll
    for (int i = 0; i < 4; ++i) {
        int col = tid * 4 + i;
        r[i] = (o[i] - mu) * rs * g[col] + b[col];
    }
    ov.x = r[0]; ov.y = r[1]; ov.z = r[2]; ov.w = r[3];
    *(float4 *)(out + (long)row * 1024 + tid * 4) = ov;
}

// ---------------------------------------------------------------------------
// Launch
// ---------------------------------------------------------------------------
extern "C" void kernel_launch(void *const *d_in, const int *in_sizes, int n_in,
                              void *d_out, int out_size, void *d_ws,
                              size_t ws_size, hipStream_t stream) {
    const float *x = (const float *)d_in[0];
    const float *wq = (const float *)d_in[1];
    const float *wk = (const float *)d_in[2];
    const float *wv = (const float *)d_in[3];
    const float *fw_w1 = (const float *)d_in[4];
    const float *fw_b1 = (const float *)d_in[5];
    const float *fw_w2 = (const float *)d_in[6];
    const float *fw_b2 = (const float *)d_in[7];
    const float *fw_lng = (const float *)d_in[8];
    const float *fw_lnb = (const float *)d_in[9];
    const float *loss_w = (const float *)d_in[10];
    const float *loss_b = (const float *)d_in[11];
    const float *ttt_g = (const float *)d_in[12];
    const float *ttt_b = (const float *)d_in[13];
    const float *wo = (const float *)d_in[14];
    const float *wg = (const float *)d_in[15];
    const float *pn_g = (const float *)d_in[16];
    const float *pn_b = (const float *)d_in[17];

    const long MAT = 2048L * 1024L;
    float *q_ws = (float *)d_ws;
    float *k_ws = q_ws + MAT;
    float *v_ws = k_ws + MAT;
    float *out_ws = v_ws + MAT;
    float *ln_ws = k_ws;
    float *gated_ws = v_ws;

    dim3 gg(1024 / 64, 2048 / 64), bt(256);
    hipLaunchKernelGGL(gemm_f32, gg, bt, 0, stream, x, wq, q_ws,
                       (const float *)nullptr, 2048, 1024, 1024, 0);
    hipLaunchKernelGGL(gemm_f32, gg, bt, 0, stream, x, wk, k_ws,
                       (const float *)nullptr, 2048, 1024, 1024, 0);
    hipLaunchKernelGGL(gemm_f32, gg, bt, 0, stream, x, wv, v_ws,
                       (const float *)nullptr, 2048, 1024, 1024, 0);

    (void)hipFuncSetAttribute((const void *)ttt_scan,
                              hipFuncAttributeMaxDynamicSharedMemorySize,
                              LDS_SCAN);
    hipLaunchKernelGGL(ttt_scan, dim3(16), dim3(64), LDS_SCAN, stream,
                       q_ws, k_ws, v_ws, out_ws, fw_w1, fw_b1, fw_w2, fw_b2,
                       fw_lng, fw_lnb, loss_w, loss_b, ttt_g, ttt_b);

    hipLaunchKernelGGL(row_ln, dim3(2048), dim3(256), 0, stream, out_ws, ln_ws,
                       pn_g, pn_b);
    hipLaunchKernelGGL(gemm_f32, gg, bt, 0, stream, x, wg, gated_ws, ln_ws,
                       2048, 1024, 1024, 1);
    hipLaunchKernelGGL(gemm_f32, gg, bt, 0, stream, gated_ws, wo,
                       (float *)d_out, (const float *)nullptr, 2048, 1024,
                       1024, 0);
}